// Round 8
// baseline (119.800 us; speedup 1.0000x reference)
//
#include <hip/hip_runtime.h>

typedef __bf16 v8bf __attribute__((ext_vector_type(8)));
typedef float v4f __attribute__((ext_vector_type(4)));
typedef unsigned int v4u __attribute__((ext_vector_type(4)));

static constexpr int NR = 8192;
static constexpr int DD = 256;
static constexpr float INV_T = 1.0f / 0.3f;

// workspace layout (bytes)
static constexpr size_t FBF_OFF = 0;                    // 4 MiB bf16 normalized f
static constexpr size_t SE_OFF  = 4194304;              // 8192 f32 sum-of-exp
static constexpr size_t G_OFF   = SE_OFF + 8192 * 4;    // 10*256 f32 class sums
static constexpr size_t CNT_OFF = G_OFF + 2560 * 4;     // 16 i32 class counts
static constexpr size_t GP_OFF  = CNT_OFF + 64;         // 256*2560 f32 partials (2.6 MB)

__global__ __launch_bounds__(256) void k_zero(float* se, int* cnt, float* out) {
    const int i = blockIdx.x * 256 + threadIdx.x;
    for (int idx = i; idx < 8192; idx += gridDim.x * 256) se[idx] = 0.f;
    if (i < 16) cnt[i] = 0;
    if (i == 0) out[0] = 0.f;
}

// Pure streaming L2-normalize: one row per wave, 2048 blocks.
__global__ __launch_bounds__(256) void k_norm(const float* __restrict__ x,
                                              unsigned short* __restrict__ fbf) {
    const int w = threadIdx.x >> 6, l = threadIdx.x & 63;
    const int row = blockIdx.x * 4 + w;
    const float4 v = *reinterpret_cast<const float4*>(x + row * DD + l * 4);
    float ss = v.x * v.x + v.y * v.y + v.z * v.z + v.w * v.w;
    #pragma unroll
    for (int m = 1; m < 64; m <<= 1) ss += __shfl_xor(ss, m, 64);
    const float rn = 1.0f / fmaxf(sqrtf(ss), 1e-12f);
    union { __bf16 h[4]; uint2 u; } pk;
    pk.h[0] = (__bf16)(v.x * rn); pk.h[1] = (__bf16)(v.y * rn);
    pk.h[2] = (__bf16)(v.z * rn); pk.h[3] = (__bf16)(v.w * rn);
    *reinterpret_cast<uint2*>(fbf + row * DD + l * 4) = pk.u;
}

// Class-sum partials: 256 blocks x 32 rows, register acc, COALESCED partial
// writes (no global atomics - R7's 655K contended atomics were ~27 us).
__global__ __launch_bounds__(256) void k_gsum(const unsigned short* __restrict__ fbf,
                                              const int* __restrict__ lab,
                                              float* __restrict__ gpart,
                                              int* __restrict__ cnt) {
    __shared__ float gsh[2560];
    __shared__ int csh[16];
    const int tid = threadIdx.x;
    const int w = tid >> 6, l = tid & 63;
    for (int i = tid; i < 2560; i += 256) gsh[i] = 0.f;
    if (tid < 16) csh[tid] = 0;
    __syncthreads();

    float acc[10][4];
    int cc[10];
    #pragma unroll
    for (int c = 0; c < 10; ++c) {
        acc[c][0] = acc[c][1] = acc[c][2] = acc[c][3] = 0.f;
        cc[c] = 0;
    }
    #pragma unroll
    for (int it = 0; it < 8; ++it) {
        const int row = blockIdx.x * 32 + w * 8 + it;
        const int lb = lab[row];
        const uint2 u = *reinterpret_cast<const uint2*>(fbf + row * DD + l * 4);
        const float f0 = __uint_as_float(u.x << 16);
        const float f1 = __uint_as_float(u.x & 0xffff0000u);
        const float f2 = __uint_as_float(u.y << 16);
        const float f3 = __uint_as_float(u.y & 0xffff0000u);
        #pragma unroll
        for (int c = 0; c < 10; ++c) {
            const bool m = (lb == c);
            acc[c][0] += m ? f0 : 0.f;
            acc[c][1] += m ? f1 : 0.f;
            acc[c][2] += m ? f2 : 0.f;
            acc[c][3] += m ? f3 : 0.f;
            cc[c] += m ? 1 : 0;
        }
    }
    #pragma unroll
    for (int c = 0; c < 10; ++c) {
        float* gb = &gsh[c * DD + l * 4];
        atomicAdd(gb + 0, acc[c][0]); atomicAdd(gb + 1, acc[c][1]);
        atomicAdd(gb + 2, acc[c][2]); atomicAdd(gb + 3, acc[c][3]);
        if (l == 0) atomicAdd(&csh[c], cc[c]);
    }
    __syncthreads();
    float* gp = gpart + (size_t)blockIdx.x * 2560;
    for (int i = tid; i < 2560; i += 256) gp[i] = gsh[i];
    if (tid < 10) atomicAdd(&cnt[tid], csh[tid]);
}

// Reduce 256 partials -> g[2560]. 10 blocks x 256 threads, coalesced reads.
__global__ __launch_bounds__(256) void k_gsum2(const float* __restrict__ gpart,
                                               float* __restrict__ g) {
    const int i = blockIdx.x * 256 + threadIdx.x;
    float s = 0.f;
    #pragma unroll 8
    for (int p = 0; p < 256; ++p) s += gpart[(size_t)p * 2560 + i];
    g[i] = s;
}

// Gram + exp row-sum. Grid 512 = 32 row-blocks x 16 col-chunks, 2 blocks/CU.
// REG-STAGED double buffer (T14): global->VGPR (issued 2 steps early, pinned)
// -> ds_write (swizzled) -> one lgkmcnt(0)+s_barrier per step. No
// global_load_lds => no compiler vmcnt(0) drain against the LDS queue; all
// global-load waits are compiler-managed fine-grained vmcnt on named regs.
__global__ __launch_bounds__(256, 2) void k_score(const unsigned short* __restrict__ fbf,
                                                  float* __restrict__ sumexp) {
    __shared__ unsigned short Bsh[2][32 * 256];   // 2 x 16 KiB
    const int tid = threadIdx.x;
    const int w = tid >> 6, l = tid & 63;
    const int ll = l & 15, lh = l >> 4;
    const int rb = blockIdx.x & 31;
    const int cc = blockIdx.x >> 5;
    const int row0 = rb * 256 + w * 64;
    const int c0 = cc * 512;
    const char* fbase = (const char*)fbf;

    // A fragments: 4 row-frags x 8 k-steps, 16B/lane, register-resident.
    v4u a[4][8];
    #pragma unroll
    for (int mr = 0; mr < 4; ++mr) {
        const char* rp = fbase + (size_t)(row0 + mr * 16 + ll) * 512 + lh * 16;
        #pragma unroll
        for (int ks = 0; ks < 8; ++ks) {
            a[mr][ks] = *reinterpret_cast<const v4u*>(rp + ks * 64);
            asm volatile("" : "+v"(a[mr][ks]));
        }
    }

    float se[4][4];
    #pragma unroll
    for (int mr = 0; mr < 4; ++mr)
        #pragma unroll
        for (int r = 0; r < 4; ++r) se[mr][r] = 0.f;

    const unsigned wbase = (unsigned)w * 4096u;
    // per-lane stage geometry: o = wbase + t*1024 + l*16; col = o>>9; kb = o&511
    // global src (LINEAR, coalesced): (c0 + s*32 + col)*512 + kb
    // LDS dst (XOR-swizzled write; read side uses the same XOR):
    //   col*512 + (kb ^ ((col&7)<<4))
    unsigned scol[4], skb[4], sdst[4];
    #pragma unroll
    for (int t = 0; t < 4; ++t) {
        const unsigned o = wbase + t * 1024u + (unsigned)l * 16u;
        scol[t] = o >> 9;
        skb[t]  = o & 511u;
        sdst[t] = scol[t] * 512u + (skb[t] ^ ((scol[t] & 7u) << 4));
    }

    auto load_set = [&](v4u (&r)[4], int s) {
        #pragma unroll
        for (int t = 0; t < 4; ++t) {
            const char* gp = fbase + (size_t)(c0 + s * 32 + (int)scol[t]) * 512 + skb[t];
            r[t] = *reinterpret_cast<const v4u*>(gp);
            asm volatile("" : "+v"(r[t]));   // pin issue point (early)
        }
    };
    auto write_set = [&](v4u (&r)[4], int buf) {
        char* lb = (char*)&Bsh[buf][0];
        #pragma unroll
        for (int t = 0; t < 4; ++t)
            *reinterpret_cast<v4u*>(lb + sdst[t]) = r[t];
    };

    v4u rA[4], rB[4];

    // prologue: buf0 <- s0; issue s1 loads; sync
    load_set(rA, 0);
    write_set(rA, 0);            // compiler waits vmcnt on rA only
    load_set(rB, 1);
    asm volatile("s_waitcnt lgkmcnt(0)" ::: "memory");
    __builtin_amdgcn_s_barrier();

    auto step = [&](int s, v4u (&Lset)[4], v4u (&Wset)[4]) {
        if (s < 14) load_set(Lset, s + 2);    // issue early: latency spans step
        const char* lb = (const char*)&Bsh[s & 1][0];
        v4f acc[4][2];
        #pragma unroll
        for (int mr = 0; mr < 4; ++mr) {
            acc[mr][0] = (v4f){0.f, 0.f, 0.f, 0.f};
            acc[mr][1] = (v4f){0.f, 0.f, 0.f, 0.f};
        }
        __builtin_amdgcn_s_setprio(1);
        #pragma unroll
        for (int ks = 0; ks < 8; ++ks) {
            const unsigned kb = (unsigned)(ks * 64 + lh * 16);
            const unsigned ad = (unsigned)ll * 512u + (kb ^ (((unsigned)ll & 7u) << 4));
            const v8bf b0 = *reinterpret_cast<const v8bf*>(lb + ad);
            const v8bf b1 = *reinterpret_cast<const v8bf*>(lb + ad + 8192);
            #pragma unroll
            for (int mr = 0; mr < 4; ++mr) {
                const v8bf av = __builtin_bit_cast(v8bf, a[mr][ks]);
                acc[mr][0] = __builtin_amdgcn_mfma_f32_16x16x32_bf16(av, b0, acc[mr][0], 0, 0, 0);
                acc[mr][1] = __builtin_amdgcn_mfma_f32_16x16x32_bf16(av, b1, acc[mr][1], 0, 0, 0);
            }
        }
        __builtin_amdgcn_s_setprio(0);
        #pragma unroll
        for (int mr = 0; mr < 4; ++mr)
            #pragma unroll
            for (int nr = 0; nr < 2; ++nr)
                #pragma unroll
                for (int r = 0; r < 4; ++r)
                    se[mr][r] += __expf(acc[mr][nr][r] * INV_T);
        if (s < 15) {
            write_set(Wset, (s + 1) & 1);    // fill idle buffer for s+1
            asm volatile("s_waitcnt lgkmcnt(0)" ::: "memory");
            __builtin_amdgcn_s_barrier();
        }
    };

    #pragma unroll 1
    for (int ss = 0; ss < 8; ++ss) {         // static reg-set ping-pong (rule #20)
        step(2 * ss,     rA, rB);
        step(2 * ss + 1, rB, rA);
    }

    // Row sums: reduce over 16 column-lanes (col = lane&15, row = (lane>>4)*4 + r).
    #pragma unroll
    for (int mr = 0; mr < 4; ++mr)
        #pragma unroll
        for (int r = 0; r < 4; ++r) {
            float v = se[mr][r];
            v += __shfl_xor(v, 1, 64);
            v += __shfl_xor(v, 2, 64);
            v += __shfl_xor(v, 4, 64);
            v += __shfl_xor(v, 8, 64);
            if (ll == 0)
                atomicAdd(&sumexp[row0 + mr * 16 + lh * 4 + r], v);
        }
}

// Per-row finalize, one 16-lane group per row (16 rows/block, 512 blocks).
__global__ __launch_bounds__(256) void k_final(const unsigned short* __restrict__ fbf,
                                               const float* __restrict__ sumexp,
                                               const float* __restrict__ g,
                                               const int* __restrict__ cnt,
                                               const int* __restrict__ lab,
                                               float* __restrict__ out) {
    __shared__ float lsum[16];
    const int tid = threadIdx.x;
    const int grp = tid >> 4, gl = tid & 15;
    const int row = blockIdx.x * 16 + grp;
    const int lb = lab[row];
    const char* rp = (const char*)fbf + (size_t)row * 512 + gl * 32;
    const uint4 u0 = *reinterpret_cast<const uint4*>(rp);
    const uint4 u1 = *reinterpret_cast<const uint4*>(rp + 16);
    const float* gp = g + lb * 256 + gl * 16;
    const float4 g0 = *reinterpret_cast<const float4*>(gp + 0);
    const float4 g1 = *reinterpret_cast<const float4*>(gp + 4);
    const float4 g2 = *reinterpret_cast<const float4*>(gp + 8);
    const float4 g3 = *reinterpret_cast<const float4*>(gp + 12);
    float d = 0.f;
    auto dot8 = [&](const uint4& u, const float4& aa, const float4& bb) {
        d += __uint_as_float(u.x << 16) * aa.x + __uint_as_float(u.x & 0xffff0000u) * aa.y
           + __uint_as_float(u.y << 16) * aa.z + __uint_as_float(u.y & 0xffff0000u) * aa.w
           + __uint_as_float(u.z << 16) * bb.x + __uint_as_float(u.z & 0xffff0000u) * bb.y
           + __uint_as_float(u.w << 16) * bb.z + __uint_as_float(u.w & 0xffff0000u) * bb.w;
    };
    dot8(u0, g0, g1);
    dot8(u1, g2, g3);
    d += __shfl_xor(d, 1, 64);
    d += __shfl_xor(d, 2, 64);
    d += __shfl_xor(d, 4, 64);
    d += __shfl_xor(d, 8, 64);
    if (gl == 0) {
        const int pc = cnt[lb] - 1;
        const float mp = (d - 1.0f) * INV_T / (float)(pc > 1 ? pc : 1);
        const float denom = sumexp[row] - __expf(INV_T);
        lsum[grp] = (pc > 0) ? (logf(denom) - mp) : 0.f;
    }
    __syncthreads();
    if (tid == 0) {
        float s = 0.f;
        #pragma unroll
        for (int i = 0; i < 16; ++i) s += lsum[i];
        atomicAdd(out, s);
    }
}

extern "C" void kernel_launch(void* const* d_in, const int* in_sizes, int n_in,
                              void* d_out, int out_size, void* d_ws, size_t ws_size,
                              hipStream_t stream) {
    const float* feat = (const float*)d_in[0];
    const int* labels = (const int*)d_in[1];
    float* out = (float*)d_out;
    char* ws = (char*)d_ws;
    unsigned short* fbf = (unsigned short*)(ws + FBF_OFF);
    float* se    = (float*)(ws + SE_OFF);
    float* g     = (float*)(ws + G_OFF);
    int* cnt     = (int*)(ws + CNT_OFF);
    float* gpart = (float*)(ws + GP_OFF);

    k_zero<<<dim3(8), dim3(256), 0, stream>>>(se, cnt, out);
    k_norm<<<dim3(2048), dim3(256), 0, stream>>>(feat, fbf);
    k_gsum<<<dim3(256), dim3(256), 0, stream>>>(fbf, labels, gpart, cnt);
    k_gsum2<<<dim3(10), dim3(256), 0, stream>>>(gpart, g);
    k_score<<<dim3(512), dim3(256), 0, stream>>>(fbf, se);
    k_final<<<dim3(512), dim3(256), 0, stream>>>(fbf, se, g, cnt, labels, out);
}

// Round 9
// 114.398 us; speedup vs baseline: 1.0472x; 1.0472x over previous
//
#include <hip/hip_runtime.h>

typedef __bf16 v8bf __attribute__((ext_vector_type(8)));
typedef float v4f __attribute__((ext_vector_type(4)));
typedef unsigned int v4u __attribute__((ext_vector_type(4)));

static constexpr int NR = 8192;
static constexpr int DD = 256;
static constexpr float INV_T = 1.0f / 0.3f;

// workspace layout (bytes). NOTE: separt reuses gpart's region — k_gsum/k_gsum2
// fully consume gpart before k_score runs (stream order), no aliasing hazard.
static constexpr size_t FBF_OFF = 0;                     // 4 MiB bf16 normalized f
static constexpr size_t G_OFF   = 4194304;               // 2560 f32 class sums
static constexpr size_t CNT_OFF = G_OFF + 2560 * 4;      // 16 i32 class counts
static constexpr size_t LP_OFF  = CNT_OFF + 64;          // 512 f32 k_final partials
static constexpr size_t GP_OFF  = LP_OFF + 2048;         // 256*2560 f32 gsum partials (2.6 MB)
static constexpr size_t SEP_OFF = GP_OFF;                // 8192*64 f32 separt (2 MB, reuses GP)

// Pure streaming L2-normalize: one row per wave, 2048 blocks.
__global__ __launch_bounds__(256) void k_norm(const float* __restrict__ x,
                                              unsigned short* __restrict__ fbf) {
    const int w = threadIdx.x >> 6, l = threadIdx.x & 63;
    const int row = blockIdx.x * 4 + w;
    const float4 v = *reinterpret_cast<const float4*>(x + row * DD + l * 4);
    float ss = v.x * v.x + v.y * v.y + v.z * v.z + v.w * v.w;
    #pragma unroll
    for (int m = 1; m < 64; m <<= 1) ss += __shfl_xor(ss, m, 64);
    const float rn = 1.0f / fmaxf(sqrtf(ss), 1e-12f);
    union { __bf16 h[4]; uint2 u; } pk;
    pk.h[0] = (__bf16)(v.x * rn); pk.h[1] = (__bf16)(v.y * rn);
    pk.h[2] = (__bf16)(v.z * rn); pk.h[3] = (__bf16)(v.w * rn);
    *reinterpret_cast<uint2*>(fbf + row * DD + l * 4) = pk.u;
}

// Class-sum partials: 256 blocks x 32 rows, register acc, coalesced writes.
__global__ __launch_bounds__(256) void k_gsum(const unsigned short* __restrict__ fbf,
                                              const int* __restrict__ lab,
                                              float* __restrict__ gpart) {
    __shared__ float gsh[2560];
    const int tid = threadIdx.x;
    const int w = tid >> 6, l = tid & 63;
    for (int i = tid; i < 2560; i += 256) gsh[i] = 0.f;
    __syncthreads();
    float acc[10][4];
    #pragma unroll
    for (int c = 0; c < 10; ++c)
        acc[c][0] = acc[c][1] = acc[c][2] = acc[c][3] = 0.f;
    #pragma unroll
    for (int it = 0; it < 8; ++it) {
        const int row = blockIdx.x * 32 + w * 8 + it;
        const int lb = lab[row];
        const uint2 u = *reinterpret_cast<const uint2*>(fbf + row * DD + l * 4);
        const float f0 = __uint_as_float(u.x << 16);
        const float f1 = __uint_as_float(u.x & 0xffff0000u);
        const float f2 = __uint_as_float(u.y << 16);
        const float f3 = __uint_as_float(u.y & 0xffff0000u);
        #pragma unroll
        for (int c = 0; c < 10; ++c) {
            const bool m = (lb == c);
            acc[c][0] += m ? f0 : 0.f;
            acc[c][1] += m ? f1 : 0.f;
            acc[c][2] += m ? f2 : 0.f;
            acc[c][3] += m ? f3 : 0.f;
        }
    }
    #pragma unroll
    for (int c = 0; c < 10; ++c) {
        float* gb = &gsh[c * DD + l * 4];
        atomicAdd(gb + 0, acc[c][0]); atomicAdd(gb + 1, acc[c][1]);
        atomicAdd(gb + 2, acc[c][2]); atomicAdd(gb + 3, acc[c][3]);
    }
    __syncthreads();
    float* gp = gpart + (size_t)blockIdx.x * 2560;
    for (int i = tid; i < 2560; i += 256) gp[i] = gsh[i];
}

// Reduce 256 partials -> g[2560]; block c also counts labels==c -> cnt[c].
__global__ __launch_bounds__(256) void k_gsum2(const float* __restrict__ gpart,
                                               const int* __restrict__ lab,
                                               float* __restrict__ g,
                                               int* __restrict__ cnt) {
    __shared__ int csh[4];
    const int tid = threadIdx.x;
    const int i = blockIdx.x * 256 + tid;
    float s = 0.f;
    #pragma unroll 8
    for (int p = 0; p < 256; ++p) s += gpart[(size_t)p * 2560 + i];
    g[i] = s;
    // count labels == blockIdx.x
    int c = 0;
    #pragma unroll 8
    for (int q = 0; q < 32; ++q) c += (lab[q * 256 + tid] == (int)blockIdx.x) ? 1 : 0;
    #pragma unroll
    for (int m = 1; m < 64; m <<= 1) c += __shfl_xor(c, m, 64);
    if ((tid & 63) == 0) csh[tid >> 6] = c;
    __syncthreads();
    if (tid == 0) cnt[blockIdx.x] = csh[0] + csh[1] + csh[2] + csh[3];
}

// Gram + exp row-sum, STAGE-ONCE structure (no inner-loop barriers).
// Grid 2048 = 32 row-blocks x 64 col-panels. Block tile: 256 rows x 128 cols.
// B panel (128 cols x 512B = 64 KiB) staged ONCE via global_load_lds (linear
// dest + pre-swizzled source, rule #21), ONE __syncthreads, then a barrier-free
// hot loop: 8 col-frags x {8 ds_read_b128 (reg double-buffered) + 32 MFMA +
// 16 exp}. fbf (4 MiB) is L2-resident per XCD, so panel re-fetch is cheap.
// Row partial sums -> separt[row][64] non-atomic (no zero-init needed).
__global__ __launch_bounds__(256, 2) void k_score(const unsigned short* __restrict__ fbf,
                                                  float* __restrict__ separt) {
    __shared__ unsigned short Bsh[128 * 256];   // 64 KiB panel
    const int tid = threadIdx.x;
    const int w = tid >> 6, l = tid & 63;
    const int ll = l & 15, lh = l >> 4;
    const int rb = blockIdx.x >> 6;
    const int cb = blockIdx.x & 63;
    const int row0 = rb * 256 + w * 64;
    const int c0 = cb * 128;
    const char* fbase = (const char*)fbf;
    char* lds = (char*)&Bsh[0];

    // Stage the whole 128-col panel: wave w covers panel cols [w*32, w*32+32).
    {
        const unsigned wbase = (unsigned)w * 16384u;
        #pragma unroll
        for (int t = 0; t < 16; ++t) {
            const unsigned o   = wbase + t * 1024u + (unsigned)l * 16u;
            const unsigned col = o >> 9;                  // panel col 0..127
            const unsigned kb  = o & 511u;
            const unsigned src = kb ^ ((col & 7u) << 4);  // pre-swizzled source
            const char* gp = fbase + (size_t)(c0 + (int)col) * 512 + src;
            __builtin_amdgcn_global_load_lds(
                (const __attribute__((address_space(1))) void*)gp,
                (__attribute__((address_space(3))) void*)(lds + o),
                16, 0, 0);
        }
    }

    // A fragments: 4 row-frags x 8 k-steps, 16B/lane, register-resident.
    v4u a[4][8];
    #pragma unroll
    for (int mr = 0; mr < 4; ++mr) {
        const char* rp = fbase + (size_t)(row0 + mr * 16 + ll) * 512 + lh * 16;
        #pragma unroll
        for (int ks = 0; ks < 8; ++ks) {
            a[mr][ks] = *reinterpret_cast<const v4u*>(rp + ks * 64);
            asm volatile("" : "+v"(a[mr][ks]));
        }
    }

    float se[4][4];
    #pragma unroll
    for (int mr = 0; mr < 4; ++mr)
        #pragma unroll
        for (int r = 0; r < 4; ++r) se[mr][r] = 0.f;

    __syncthreads();   // panel staged (single drain for the whole kernel)

    // B-frag read: panel col = cf*16 + ll, k-bytes ks*64 + lh*16, read-side XOR.
    auto load_b = [&](v4u (&b)[8], int cf) {
        const char* base = lds + cf * 8192 + (unsigned)ll * 512u;
        #pragma unroll
        for (int ks = 0; ks < 8; ++ks) {
            const unsigned kb = (unsigned)(ks * 64 + lh * 16);
            b[ks] = *reinterpret_cast<const v4u*>(base + (kb ^ (((unsigned)ll & 7u) << 4)));
        }
    };
    auto compute = [&](v4u (&b)[8]) {
        v4f acc[4];
        #pragma unroll
        for (int mr = 0; mr < 4; ++mr) acc[mr] = (v4f){0.f, 0.f, 0.f, 0.f};
        #pragma unroll
        for (int ks = 0; ks < 8; ++ks) {
            const v8bf bv = __builtin_bit_cast(v8bf, b[ks]);
            #pragma unroll
            for (int mr = 0; mr < 4; ++mr)
                acc[mr] = __builtin_amdgcn_mfma_f32_16x16x32_bf16(
                    __builtin_bit_cast(v8bf, a[mr][ks]), bv, acc[mr], 0, 0, 0);
        }
        #pragma unroll
        for (int mr = 0; mr < 4; ++mr)
            #pragma unroll
            for (int r = 0; r < 4; ++r)
                se[mr][r] += __expf(acc[mr][r] * INV_T);
    };

    // Static register double-buffer over 8 col-frags (rule #20: named sets).
    v4u bA[8], bB[8];
    load_b(bA, 0);
    #pragma unroll
    for (int cf2 = 0; cf2 < 4; ++cf2) {
        load_b(bB, 2 * cf2 + 1);
        compute(bA);
        if (cf2 < 3) load_b(bA, 2 * cf2 + 2);
        compute(bB);
    }

    // Row sums: reduce over 16 column-lanes (col = lane&15, row = (lane>>4)*4+r).
    #pragma unroll
    for (int mr = 0; mr < 4; ++mr)
        #pragma unroll
        for (int r = 0; r < 4; ++r) {
            float v = se[mr][r];
            v += __shfl_xor(v, 1, 64);
            v += __shfl_xor(v, 2, 64);
            v += __shfl_xor(v, 4, 64);
            v += __shfl_xor(v, 8, 64);
            if (ll == 0)
                separt[(size_t)(row0 + mr * 16 + lh * 4 + r) * 64 + cb] = v;
        }
}

// Per-row finalize, one 16-lane group per row (16 rows/block, 512 blocks).
// Writes non-atomic block partials to lpart[512].
__global__ __launch_bounds__(256) void k_final(const unsigned short* __restrict__ fbf,
                                               const float* __restrict__ separt,
                                               const float* __restrict__ g,
                                               const int* __restrict__ cnt,
                                               const int* __restrict__ lab,
                                               float* __restrict__ lpart) {
    __shared__ float lsum[16];
    const int tid = threadIdx.x;
    const int grp = tid >> 4, gl = tid & 15;
    const int row = blockIdx.x * 16 + grp;
    const int lb = lab[row];
    const char* rp = (const char*)fbf + (size_t)row * 512 + gl * 32;
    const uint4 u0 = *reinterpret_cast<const uint4*>(rp);
    const uint4 u1 = *reinterpret_cast<const uint4*>(rp + 16);
    const float* gp = g + lb * 256 + gl * 16;
    const float4 g0 = *reinterpret_cast<const float4*>(gp + 0);
    const float4 g1 = *reinterpret_cast<const float4*>(gp + 4);
    const float4 g2 = *reinterpret_cast<const float4*>(gp + 8);
    const float4 g3 = *reinterpret_cast<const float4*>(gp + 12);
    float d = 0.f;
    auto dot8 = [&](const uint4& u, const float4& aa, const float4& bb) {
        d += __uint_as_float(u.x << 16) * aa.x + __uint_as_float(u.x & 0xffff0000u) * aa.y
           + __uint_as_float(u.y << 16) * aa.z + __uint_as_float(u.y & 0xffff0000u) * aa.w
           + __uint_as_float(u.z << 16) * bb.x + __uint_as_float(u.z & 0xffff0000u) * bb.y
           + __uint_as_float(u.w << 16) * bb.z + __uint_as_float(u.w & 0xffff0000u) * bb.w;
    };
    dot8(u0, g0, g1);
    dot8(u1, g2, g3);
    // denom partials: lane gl sums separt[row][gl*4 .. gl*4+3] (coalesced v4f)
    const v4f sv = *reinterpret_cast<const v4f*>(separt + (size_t)row * 64 + gl * 4);
    float dn = sv[0] + sv[1] + sv[2] + sv[3];
    #pragma unroll
    for (int m = 1; m < 16; m <<= 1) {
        d  += __shfl_xor(d, m, 64);
        dn += __shfl_xor(dn, m, 64);
    }
    if (gl == 0) {
        const int pc = cnt[lb] - 1;
        const float mp = (d - 1.0f) * INV_T / (float)(pc > 1 ? pc : 1);
        const float denom = dn - __expf(INV_T);
        lsum[grp] = (pc > 0) ? (logf(denom) - mp) : 0.f;
    }
    __syncthreads();
    if (tid == 0) {
        float s = 0.f;
        #pragma unroll
        for (int i = 0; i < 16; ++i) s += lsum[i];
        lpart[blockIdx.x] = s;
    }
}

// Single-block reduce of lpart[512] -> out[0] (direct store, no zero-init).
__global__ __launch_bounds__(256) void k_final2(const float* __restrict__ lpart,
                                                float* __restrict__ out) {
    __shared__ float wsum[4];
    const int tid = threadIdx.x;
    float s = lpart[tid] + lpart[tid + 256];
    #pragma unroll
    for (int m = 1; m < 64; m <<= 1) s += __shfl_xor(s, m, 64);
    if ((tid & 63) == 0) wsum[tid >> 6] = s;
    __syncthreads();
    if (tid == 0) out[0] = wsum[0] + wsum[1] + wsum[2] + wsum[3];
}

extern "C" void kernel_launch(void* const* d_in, const int* in_sizes, int n_in,
                              void* d_out, int out_size, void* d_ws, size_t ws_size,
                              hipStream_t stream) {
    const float* feat = (const float*)d_in[0];
    const int* labels = (const int*)d_in[1];
    float* out = (float*)d_out;
    char* ws = (char*)d_ws;
    unsigned short* fbf = (unsigned short*)(ws + FBF_OFF);
    float* g      = (float*)(ws + G_OFF);
    int* cnt      = (int*)(ws + CNT_OFF);
    float* lpart  = (float*)(ws + LP_OFF);
    float* gpart  = (float*)(ws + GP_OFF);
    float* separt = (float*)(ws + SEP_OFF);   // reuses gpart region (stream-ordered)

    k_norm<<<dim3(2048), dim3(256), 0, stream>>>(feat, fbf);
    k_gsum<<<dim3(256), dim3(256), 0, stream>>>(fbf, labels, gpart);
    k_gsum2<<<dim3(10), dim3(256), 0, stream>>>(gpart, labels, g, cnt);
    k_score<<<dim3(2048), dim3(256), 0, stream>>>(fbf, separt);
    k_final<<<dim3(512), dim3(256), 0, stream>>>(fbf, separt, g, cnt, labels, lpart);
    k_final2<<<dim3(1), dim3(256), 0, stream>>>(lpart, out);
}

// Round 10
// 92.629 us; speedup vs baseline: 1.2933x; 1.2350x over previous
//
#include <hip/hip_runtime.h>

typedef __bf16 v8bf __attribute__((ext_vector_type(8)));
typedef float v4f __attribute__((ext_vector_type(4)));
typedef unsigned int v4u __attribute__((ext_vector_type(4)));

static constexpr int NR = 8192;
static constexpr int DD = 256;
static constexpr float INV_T = 1.0f / 0.3f;

// workspace layout (bytes). separt reuses gpart's region (stream-ordered).
static constexpr size_t FBF_OFF = 0;                     // 4 MiB bf16 normalized f
static constexpr size_t G_OFF   = 4194304;               // 2560 f32 class sums
static constexpr size_t CNT_OFF = G_OFF + 2560 * 4;      // 16 i32 class counts
static constexpr size_t LP_OFF  = CNT_OFF + 64;          // 512 f32 k_final partials
static constexpr size_t GP_OFF  = LP_OFF + 2048;         // 256*2560 f32 gsum partials
static constexpr size_t SEP_OFF = GP_OFF;                // 8192*16 f32 separt (512KB)

// Pure streaming L2-normalize: one row per wave, 2048 blocks.
__global__ __launch_bounds__(256) void k_norm(const float* __restrict__ x,
                                              unsigned short* __restrict__ fbf) {
    const int w = threadIdx.x >> 6, l = threadIdx.x & 63;
    const int row = blockIdx.x * 4 + w;
    const float4 v = *reinterpret_cast<const float4*>(x + row * DD + l * 4);
    float ss = v.x * v.x + v.y * v.y + v.z * v.z + v.w * v.w;
    #pragma unroll
    for (int m = 1; m < 64; m <<= 1) ss += __shfl_xor(ss, m, 64);
    const float rn = 1.0f / fmaxf(sqrtf(ss), 1e-12f);
    union { __bf16 h[4]; uint2 u; } pk;
    pk.h[0] = (__bf16)(v.x * rn); pk.h[1] = (__bf16)(v.y * rn);
    pk.h[2] = (__bf16)(v.z * rn); pk.h[3] = (__bf16)(v.w * rn);
    *reinterpret_cast<uint2*>(fbf + row * DD + l * 4) = pk.u;
}

// Class-sum partials: 256 blocks x 32 rows, register acc, coalesced writes.
__global__ __launch_bounds__(256) void k_gsum(const unsigned short* __restrict__ fbf,
                                              const int* __restrict__ lab,
                                              float* __restrict__ gpart) {
    __shared__ float gsh[2560];
    const int tid = threadIdx.x;
    const int w = tid >> 6, l = tid & 63;
    for (int i = tid; i < 2560; i += 256) gsh[i] = 0.f;
    __syncthreads();
    float acc[10][4];
    #pragma unroll
    for (int c = 0; c < 10; ++c)
        acc[c][0] = acc[c][1] = acc[c][2] = acc[c][3] = 0.f;
    #pragma unroll
    for (int it = 0; it < 8; ++it) {
        const int row = blockIdx.x * 32 + w * 8 + it;
        const int lb = lab[row];
        const uint2 u = *reinterpret_cast<const uint2*>(fbf + row * DD + l * 4);
        const float f0 = __uint_as_float(u.x << 16);
        const float f1 = __uint_as_float(u.x & 0xffff0000u);
        const float f2 = __uint_as_float(u.y << 16);
        const float f3 = __uint_as_float(u.y & 0xffff0000u);
        #pragma unroll
        for (int c = 0; c < 10; ++c) {
            const bool m = (lb == c);
            acc[c][0] += m ? f0 : 0.f;
            acc[c][1] += m ? f1 : 0.f;
            acc[c][2] += m ? f2 : 0.f;
            acc[c][3] += m ? f3 : 0.f;
        }
    }
    #pragma unroll
    for (int c = 0; c < 10; ++c) {
        float* gb = &gsh[c * DD + l * 4];
        atomicAdd(gb + 0, acc[c][0]); atomicAdd(gb + 1, acc[c][1]);
        atomicAdd(gb + 2, acc[c][2]); atomicAdd(gb + 3, acc[c][3]);
    }
    __syncthreads();
    float* gp = gpart + (size_t)blockIdx.x * 2560;
    for (int i = tid; i < 2560; i += 256) gp[i] = gsh[i];
}

// Reduce 256 partials -> g[2560]; block c also counts labels==c -> cnt[c].
__global__ __launch_bounds__(256) void k_gsum2(const float* __restrict__ gpart,
                                               const int* __restrict__ lab,
                                               float* __restrict__ g,
                                               int* __restrict__ cnt) {
    __shared__ int csh[4];
    const int tid = threadIdx.x;
    const int i = blockIdx.x * 256 + tid;
    float s = 0.f;
    #pragma unroll 8
    for (int p = 0; p < 256; ++p) s += gpart[(size_t)p * 2560 + i];
    g[i] = s;
    int c = 0;
    #pragma unroll 8
    for (int q = 0; q < 32; ++q) c += (lab[q * 256 + tid] == (int)blockIdx.x) ? 1 : 0;
    #pragma unroll
    for (int m = 1; m < 64; m <<= 1) c += __shfl_xor(c, m, 64);
    if ((tid & 63) == 0) csh[tid >> 6] = c;
    __syncthreads();
    if (tid == 0) cnt[blockIdx.x] = csh[0] + csh[1] + csh[2] + csh[3];
}

// Gram + exp row-sum: R2's PROVEN 2-phase LDS double-buffer structure (43.2us,
// VGPR 104), with ONE change: 64-col steps (2x32KB buffers, 8 steps) instead
// of 32-col (16 steps) -> half the barrier/drain events, same VGPR footprint
// (acc stays [4][2]; the 64 cols are two sequential half-passes per barrier).
// Grid 512 = 32 row-blocks x 16 col-chunks, exactly 2 blocks/CU (128KB LDS).
__global__ __launch_bounds__(256, 2) void k_score(const unsigned short* __restrict__ fbf,
                                                  float* __restrict__ separt) {
    __shared__ unsigned short Bsh[2][64 * 256];   // 2 x 32 KiB, double buffered
    const int tid = threadIdx.x;
    const int w = tid >> 6, l = tid & 63;
    const int ll = l & 15, lh = l >> 4;
    const int rb = blockIdx.x & 31;
    const int cc = blockIdx.x >> 5;
    const int row0 = rb * 256 + w * 64;
    const int c0 = cc * 512;
    const char* fbase = (const char*)fbf;

    const unsigned wbase = (unsigned)w * 8192u;   // wave w covers buffer cols [w*16, w*16+16)

    // Stage 64 cols into LDS: linear dest (HW adds lane*16), pre-swizzled
    // global source (rule #21; read side applies the same XOR).
    auto stage = [&](int buf, int s) {
        char* lb = (char*)&Bsh[buf][0];
        #pragma unroll
        for (int t = 0; t < 8; ++t) {
            const unsigned o   = wbase + t * 1024u + (unsigned)l * 16u;
            const unsigned col = o >> 9;
            const unsigned kb  = o & 511u;
            const unsigned src = kb ^ ((col & 7u) << 4);
            const char* gp = fbase + (size_t)(c0 + s * 64 + (int)col) * 512 + src;
            __builtin_amdgcn_global_load_lds(
                (const __attribute__((address_space(1))) void*)gp,
                (__attribute__((address_space(3))) void*)(lb + wbase + t * 1024u),
                16, 0, 0);
        }
    };

    stage(0, 0);   // issue first panel before A-loads (overlap)

    // A fragments: 4 row-frags x 8 k-steps, 16B/lane.
    v4u a[4][8];
    #pragma unroll
    for (int mr = 0; mr < 4; ++mr) {
        const char* rp = fbase + (size_t)(row0 + mr * 16 + ll) * 512 + lh * 16;
        #pragma unroll
        for (int ks = 0; ks < 8; ++ks) {
            a[mr][ks] = *reinterpret_cast<const v4u*>(rp + ks * 64);
            asm volatile("" : "+v"(a[mr][ks]));   // keep-alive
        }
    }

    float se[4][4];
    #pragma unroll
    for (int mr = 0; mr < 4; ++mr)
        #pragma unroll
        for (int r = 0; r < 4; ++r) se[mr][r] = 0.f;

    __syncthreads();

    #pragma unroll 1
    for (int s = 0; s < 8; ++s) {
        if (s < 7) stage((s + 1) & 1, s + 1);
        const char* lb = (const char*)&Bsh[s & 1][0];
        // two half-passes of 32 cols each (keeps acc at [4][2] = 32 VGPRs)
        #pragma unroll
        for (int h = 0; h < 2; ++h) {
            const char* hb = lb + h * 16384;
            v4f acc[4][2];
            #pragma unroll
            for (int mr = 0; mr < 4; ++mr) {
                acc[mr][0] = (v4f){0.f, 0.f, 0.f, 0.f};
                acc[mr][1] = (v4f){0.f, 0.f, 0.f, 0.f};
            }
            #pragma unroll
            for (int ks = 0; ks < 8; ++ks) {
                const unsigned kb = (unsigned)(ks * 64 + lh * 16);
                const unsigned ad = (unsigned)ll * 512u + (kb ^ (((unsigned)ll & 7u) << 4));
                const v8bf b0 = *reinterpret_cast<const v8bf*>(hb + ad);
                const v8bf b1 = *reinterpret_cast<const v8bf*>(hb + ad + 8192);
                #pragma unroll
                for (int mr = 0; mr < 4; ++mr) {
                    const v8bf av = __builtin_bit_cast(v8bf, a[mr][ks]);
                    acc[mr][0] = __builtin_amdgcn_mfma_f32_16x16x32_bf16(av, b0, acc[mr][0], 0, 0, 0);
                    acc[mr][1] = __builtin_amdgcn_mfma_f32_16x16x32_bf16(av, b1, acc[mr][1], 0, 0, 0);
                }
            }
            #pragma unroll
            for (int mr = 0; mr < 4; ++mr)
                #pragma unroll
                for (int nr = 0; nr < 2; ++nr)
                    #pragma unroll
                    for (int r = 0; r < 4; ++r)
                        se[mr][r] += __expf(acc[mr][nr][r] * INV_T);
        }
        __syncthreads();
    }

    // Row sums: reduce over 16 column-lanes (col = lane&15, row = (lane>>4)*4+r).
    #pragma unroll
    for (int mr = 0; mr < 4; ++mr)
        #pragma unroll
        for (int r = 0; r < 4; ++r) {
            float v = se[mr][r];
            v += __shfl_xor(v, 1, 64);
            v += __shfl_xor(v, 2, 64);
            v += __shfl_xor(v, 4, 64);
            v += __shfl_xor(v, 8, 64);
            if (ll == 0)
                separt[(size_t)(row0 + mr * 16 + lh * 4 + r) * 16 + cc] = v;
        }
}

// Per-row finalize, one 16-lane group per row (16 rows/block, 512 blocks).
// Writes non-atomic block partials to lpart[512].
__global__ __launch_bounds__(256) void k_final(const unsigned short* __restrict__ fbf,
                                               const float* __restrict__ separt,
                                               const float* __restrict__ g,
                                               const int* __restrict__ cnt,
                                               const int* __restrict__ lab,
                                               float* __restrict__ lpart) {
    __shared__ float lsum[16];
    const int tid = threadIdx.x;
    const int grp = tid >> 4, gl = tid & 15;
    const int row = blockIdx.x * 16 + grp;
    const int lb = lab[row];
    const char* rp = (const char*)fbf + (size_t)row * 512 + gl * 32;
    const uint4 u0 = *reinterpret_cast<const uint4*>(rp);
    const uint4 u1 = *reinterpret_cast<const uint4*>(rp + 16);
    const float* gp = g + lb * 256 + gl * 16;
    const float4 g0 = *reinterpret_cast<const float4*>(gp + 0);
    const float4 g1 = *reinterpret_cast<const float4*>(gp + 4);
    const float4 g2 = *reinterpret_cast<const float4*>(gp + 8);
    const float4 g3 = *reinterpret_cast<const float4*>(gp + 12);
    float d = 0.f;
    auto dot8 = [&](const uint4& u, const float4& aa, const float4& bb) {
        d += __uint_as_float(u.x << 16) * aa.x + __uint_as_float(u.x & 0xffff0000u) * aa.y
           + __uint_as_float(u.y << 16) * aa.z + __uint_as_float(u.y & 0xffff0000u) * aa.w
           + __uint_as_float(u.z << 16) * bb.x + __uint_as_float(u.z & 0xffff0000u) * bb.y
           + __uint_as_float(u.w << 16) * bb.z + __uint_as_float(u.w & 0xffff0000u) * bb.w;
    };
    dot8(u0, g0, g1);
    dot8(u1, g2, g3);
    float dn = separt[(size_t)row * 16 + gl];
    #pragma unroll
    for (int m = 1; m < 16; m <<= 1) {
        d  += __shfl_xor(d, m, 64);
        dn += __shfl_xor(dn, m, 64);
    }
    if (gl == 0) {
        const int pc = cnt[lb] - 1;
        const float mp = (d - 1.0f) * INV_T / (float)(pc > 1 ? pc : 1);
        const float denom = dn - __expf(INV_T);
        lsum[grp] = (pc > 0) ? (logf(denom) - mp) : 0.f;
    }
    __syncthreads();
    if (tid == 0) {
        float s = 0.f;
        #pragma unroll
        for (int i = 0; i < 16; ++i) s += lsum[i];
        lpart[blockIdx.x] = s;
    }
}

// Single-block reduce of lpart[512] -> out[0] (direct store, no zero-init).
__global__ __launch_bounds__(256) void k_final2(const float* __restrict__ lpart,
                                                float* __restrict__ out) {
    __shared__ float wsum[4];
    const int tid = threadIdx.x;
    float s = lpart[tid] + lpart[tid + 256];
    #pragma unroll
    for (int m = 1; m < 64; m <<= 1) s += __shfl_xor(s, m, 64);
    if ((tid & 63) == 0) wsum[tid >> 6] = s;
    __syncthreads();
    if (tid == 0) out[0] = wsum[0] + wsum[1] + wsum[2] + wsum[3];
}

extern "C" void kernel_launch(void* const* d_in, const int* in_sizes, int n_in,
                              void* d_out, int out_size, void* d_ws, size_t ws_size,
                              hipStream_t stream) {
    const float* feat = (const float*)d_in[0];
    const int* labels = (const int*)d_in[1];
    float* out = (float*)d_out;
    char* ws = (char*)d_ws;
    unsigned short* fbf = (unsigned short*)(ws + FBF_OFF);
    float* g      = (float*)(ws + G_OFF);
    int* cnt      = (int*)(ws + CNT_OFF);
    float* lpart  = (float*)(ws + LP_OFF);
    float* gpart  = (float*)(ws + GP_OFF);
    float* separt = (float*)(ws + SEP_OFF);   // reuses gpart region (stream-ordered)

    k_norm<<<dim3(2048), dim3(256), 0, stream>>>(feat, fbf);
    k_gsum<<<dim3(256), dim3(256), 0, stream>>>(fbf, labels, gpart);
    k_gsum2<<<dim3(10), dim3(256), 0, stream>>>(gpart, labels, g, cnt);
    k_score<<<dim3(512), dim3(256), 0, stream>>>(fbf, separt);
    k_final<<<dim3(512), dim3(256), 0, stream>>>(fbf, separt, g, cnt, labels, lpart);
    k_final2<<<dim3(1), dim3(256), 0, stream>>>(lpart, out);
}